// Round 1
// baseline (88.559 us; speedup 1.0000x reference)
//
#include <hip/hip_runtime.h>
#include <math.h>

// Problem constants (from reference):
// image: (B=32, D=64, H=64, W=128) f32
// polar_log_depths: (B=32, H=64, W=128, S=64) f32
// outputs: image_polar (B,D,Z=64,W) f32, cell_score (B,W,Z) f32, concat flat.
#define B_ 32
#define D_ 64
#define H_ 64
#define W_ 128
#define S_ 64
#define Z_ 64
#define WT 2          // w-tile per block
#define PITCH 68      // LDS row pitch (floats): mult of 4 (aligned b128), 68%32=4 -> <=2-way conflicts

__global__ __launch_bounds__(256, 2)
void polar_proj_kernel(const float* __restrict__ image,
                       const float* __restrict__ polar,
                       float* __restrict__ out_img,
                       float* __restrict__ out_cell) {
    __shared__ float sp[WT][H_][PITCH];   // raw polar -> scores -> prob (in place)
    __shared__ float im[WT][H_][PITCH];   // image slice transposed: [h][d]
    __shared__ int   s_i0[Z_];
    __shared__ float s_w[Z_];

    const int t = threadIdx.x;

    // XCD-aware bijective swizzle: consecutive logical blocks (same b, adjacent
    // w-tiles share 128B image/output lines) land on the same XCD L2.
    const int nblk = gridDim.x;          // 2048, divisible by 8
    const int cpx  = nblk >> 3;
    const int logical = (blockIdx.x & 7) * cpx + (blockIdx.x >> 3);
    const int b  = logical / (W_ / WT);
    const int w0 = (logical % (W_ / WT)) * WT;

    // interp constants: pos(z) = (log2(0.5+0.5z)+1)/6 * 63
    if (t < Z_) {
        float step = 0.5f + 0.5f * (float)t;
        float pos  = (log2f(step) + 1.0f) * (1.0f / 6.0f) * (float)(S_ - 1);
        int i0 = (int)floorf(pos);
        i0 = i0 < 0 ? 0 : (i0 > S_ - 1 ? S_ - 1 : i0);
        s_i0[t] = i0;
        s_w[t]  = pos - (float)i0;
    }

    // ---- Phase 1: issue polar loads (b128) then image gather loads (8B) ----
    const int h_row = t >> 2;            // 0..63
    const int seg   = t & 3;             // 0..3
    float4 praw[WT][4];
#pragma unroll
    for (int wt = 0; wt < WT; ++wt) {
        const float* src = polar + ((size_t)(b * H_ + h_row) * W_ + (w0 + wt)) * S_;
#pragma unroll
        for (int k = 0; k < 4; ++k)
            praw[wt][k] = *(const float4*)(src + seg * 16 + k * 4);
    }
    // image gather: lane -> d (so LDS write is conflict-free), loop -> h
    const int d_ld = t & 63;
    const int tq   = t >> 6;             // 0..3
    float2 iraw[16];
#pragma unroll
    for (int k = 0; k < 16; ++k) {
        const int hh = 4 * k + tq;
        iraw[k] = *(const float2*)(image + ((size_t)(b * D_ + d_ld) * H_ + hh) * (size_t)W_ + w0);
    }
    // store polar to LDS
#pragma unroll
    for (int wt = 0; wt < WT; ++wt)
#pragma unroll
        for (int k = 0; k < 4; ++k)
            *(float4*)&sp[wt][h_row][seg * 16 + k * 4] = praw[wt][k];
    __syncthreads();   // raw polar + interp tables ready

    // ---- Phase 2: interpolate to registers, then overwrite LDS with scores ----
    float sc[WT][16];
#pragma unroll
    for (int j = 0; j < 16; ++j) {
        const int z  = seg * 16 + j;
        const int i0 = s_i0[z];
        const int i1 = (i0 + 1 > S_ - 1) ? (S_ - 1) : (i0 + 1);
        const float wgt = s_w[z];
#pragma unroll
        for (int wt = 0; wt < WT; ++wt) {
            const float v0 = sp[wt][h_row][i0];
            const float v1 = sp[wt][h_row][i1];
            sc[wt][j] = v0 * (1.0f - wgt) + v1 * wgt;
        }
    }
    __syncthreads();   // all raw reads done; safe to overwrite
#pragma unroll
    for (int wt = 0; wt < WT; ++wt)
#pragma unroll
        for (int j = 0; j < 16; ++j)
            sp[wt][h_row][seg * 16 + j] = sc[wt][j];
    __syncthreads();   // scores ready

    // ---- Phase 3: softmax over h per z (4 lanes per z), prob in place ----
    const int z_sm = t >> 2;             // 0..63
    const int q    = t & 3;              // owns h = q + 4i
#pragma unroll
    for (int wt = 0; wt < WT; ++wt) {
        float stash[16];
        float m = -1e30f;
#pragma unroll
        for (int i = 0; i < 16; ++i) {
            const float v = sp[wt][q + 4 * i][z_sm];
            stash[i] = v;
            m = fmaxf(m, v);
        }
        m = fmaxf(m, __shfl_xor(m, 1));
        m = fmaxf(m, __shfl_xor(m, 2));
        float s = 0.0f;
#pragma unroll
        for (int i = 0; i < 16; ++i) {
            const float e = __expf(stash[i] - m);
            stash[i] = e;
            s += e;
        }
        s += __shfl_xor(s, 1);
        s += __shfl_xor(s, 2);
        const float inv = 1.0f / s;
#pragma unroll
        for (int i = 0; i < 16; ++i)
            sp[wt][q + 4 * i][z_sm] = stash[i] * inv;
        if (q == 0)
            out_cell[((size_t)b * W_ + (w0 + wt)) * Z_ + z_sm] = m + logf(s);
    }

    // ---- Phase 4: stage image slice (transposed [h][d]) ----
#pragma unroll
    for (int k = 0; k < 16; ++k) {
        const int hh = 4 * k + tq;
        im[0][hh][d_ld] = iraw[k].x;
        im[1][hh][d_ld] = iraw[k].y;
    }
    __syncthreads();   // prob + image ready

    // ---- Phase 5: GEMM out[d,z] = sum_h im[h][d] * prob[h][z], 4x4 tile/thread ----
    const int d0 = (t >> 4) << 2;        // 0,4,...,60
    const int z0 = (t & 15) << 2;        // 0,4,...,60
    float acc[WT][4][4] = {};
#pragma unroll 4
    for (int h = 0; h < H_; ++h) {
#pragma unroll
        for (int wt = 0; wt < WT; ++wt) {
            const float4 pv = *(const float4*)&sp[wt][h][z0];
            const float4 iv = *(const float4*)&im[wt][h][d0];
            const float pa[4] = {pv.x, pv.y, pv.z, pv.w};
            const float ia[4] = {iv.x, iv.y, iv.z, iv.w};
#pragma unroll
            for (int i = 0; i < 4; ++i)
#pragma unroll
                for (int j = 0; j < 4; ++j)
                    acc[wt][i][j] += ia[i] * pa[j];
        }
    }

    // ---- Phase 6: write image_polar (float2 over w) ----
#pragma unroll
    for (int i = 0; i < 4; ++i)
#pragma unroll
        for (int j = 0; j < 4; ++j) {
            float2 o;
            o.x = acc[0][i][j];
            o.y = acc[1][i][j];
            *(float2*)(out_img + (((size_t)(b * D_ + d0 + i)) * Z_ + (z0 + j)) * W_ + w0) = o;
        }
}

extern "C" void kernel_launch(void* const* d_in, const int* in_sizes, int n_in,
                              void* d_out, int out_size, void* d_ws, size_t ws_size,
                              hipStream_t stream) {
    const float* image = (const float*)d_in[0];
    const float* polar = (const float*)d_in[1];
    float* out_img  = (float*)d_out;
    float* out_cell = out_img + (size_t)B_ * D_ * Z_ * W_;   // 16,777,216
    dim3 grid(B_ * (W_ / WT));   // 2048 blocks
    polar_proj_kernel<<<grid, 256, 0, stream>>>(image, polar, out_img, out_cell);
}

// Round 2
// 78.355 us; speedup vs baseline: 1.1302x; 1.1302x over previous
//
#include <hip/hip_runtime.h>
#include <hip/hip_bf16.h>
#include <math.h>

// image: (B=32, D=64, H=64, W=128) f32
// polar_log_depths: (B=32, H=64, W=128, S=64) f32
// outputs: image_polar (B,D,Z=64,W) f32, cell_score (B,W,Z) f32, concat flat.
#define B_ 32
#define D_ 64
#define H_ 64
#define W_ 128
#define S_ 64
#define Z_ 64
#define WT 2
#define PU 68     // f32 pitch of raw-polar buffer (272 B rows, 16B aligned)
#define PA 72     // bf16 pitch of A/B operand buffers (144 B rows, 16B aligned)

typedef __attribute__((ext_vector_type(8))) short bf16x8;
typedef __attribute__((ext_vector_type(4))) float f32x4;

__global__ __launch_bounds__(256, 3)
void polar_proj_kernel(const float* __restrict__ image,
                       const float* __restrict__ polar,
                       float* __restrict__ out_img,
                       float* __restrict__ out_cell) {
    // U (raw polar f32) is later overwritten by pbT (prob^T bf16) — aliased.
    __shared__ __align__(16) unsigned char smemU[WT * H_ * PU * 4];     // 34816 B
    __shared__ __align__(16) __hip_bfloat16 imA[WT][D_][PA];            // 18432 B
    float (*U)[H_][PU] = reinterpret_cast<float (*)[H_][PU]>(smemU);
    __hip_bfloat16 (*pbT)[Z_][PA] =
        reinterpret_cast<__hip_bfloat16 (*)[Z_][PA]>(smemU);            // [z][h]

    const int t = threadIdx.x;

    // XCD-bijective swizzle: adjacent w-tiles (shared 128B image/output lines)
    // stay on one XCD's L2. grid=2048, divisible by 8.
    const int nblk = gridDim.x;
    const int cpx  = nblk >> 3;
    const int logical = (blockIdx.x & 7) * cpx + (blockIdx.x >> 3);
    const int b  = logical / (W_ / WT);
    const int w0 = (logical % (W_ / WT)) * WT;

    // ---- Phase 1: global loads. Polar rows coalesced b128; image 8B gathers
    // (L2/L3-served) issued early so latency hides under interp/softmax. ----
    const int h_row = t >> 2;            // 0..63
    const int seg   = t & 3;             // quarter of the S row
    float4 praw[WT][4];
#pragma unroll
    for (int wt = 0; wt < WT; ++wt) {
        const float* src = polar + ((size_t)(b * H_ + h_row) * W_ + (w0 + wt)) * S_;
#pragma unroll
        for (int k = 0; k < 4; ++k)
            praw[wt][k] = *(const float4*)(src + seg * 16 + k * 4);
    }
    const int h_ld = t & 63;             // lane -> h: conflict-free imA stores
    const int tq   = t >> 6;
    float2 iraw[16];
#pragma unroll
    for (int k = 0; k < 16; ++k) {
        const int d = 4 * k + tq;
        iraw[k] = *(const float2*)(image + ((size_t)(b * D_ + d) * H_ + h_ld) * (size_t)W_ + w0);
    }
#pragma unroll
    for (int wt = 0; wt < WT; ++wt)
#pragma unroll
        for (int k = 0; k < 4; ++k)
            *(float4*)&U[wt][h_row][seg * 16 + k * 4] = praw[wt][k];
    __syncthreads();   // raw polar ready

    // ---- Phase 2: fused interp + softmax. Thread owns (z, q); reads raw
    // directly (scores never round-trip LDS). 4 lanes cooperate per z. ----
    const int z_sm = t >> 2;             // 0..63
    const int q    = t & 3;              // owns h = q + 4i
    float posf = (log2f(0.5f + 0.5f * (float)z_sm) + 1.0f) * 10.5f;  // (63/6)
    int i0 = (int)floorf(posf);
    i0 = i0 < 0 ? 0 : (i0 > S_ - 1 ? S_ - 1 : i0);
    const int i1 = (i0 + 1 > S_ - 1) ? (S_ - 1) : (i0 + 1);
    const float wq = posf - (float)i0;

    float stash[WT][16];
    float inv[WT];
#pragma unroll
    for (int wt = 0; wt < WT; ++wt) {
        float m = -1e30f;
#pragma unroll
        for (int i = 0; i < 16; ++i) {
            const int h = q + 4 * i;
            const float v0 = U[wt][h][i0];
            const float v1 = U[wt][h][i1];
            const float sc = v0 + wq * (v1 - v0);
            stash[wt][i] = sc;
            m = fmaxf(m, sc);
        }
        m = fmaxf(m, __shfl_xor(m, 1));
        m = fmaxf(m, __shfl_xor(m, 2));
        float s = 0.0f;
#pragma unroll
        for (int i = 0; i < 16; ++i) {
            const float e = __expf(stash[wt][i] - m);
            stash[wt][i] = e;
            s += e;
        }
        s += __shfl_xor(s, 1);
        s += __shfl_xor(s, 2);
        inv[wt] = 1.0f / s;
        if (q == 0)
            out_cell[((size_t)b * W_ + (w0 + wt)) * Z_ + z_sm] = m + logf(s);
    }
    __syncthreads();   // all raw-polar reads done; safe to overwrite with pbT

    // ---- Phase 3: write prob^T bf16 (B operand) + image bf16 (A operand) ----
#pragma unroll
    for (int wt = 0; wt < WT; ++wt)
#pragma unroll
        for (int i = 0; i < 16; ++i)
            pbT[wt][z_sm][q + 4 * i] = __float2bfloat16(stash[wt][i] * inv[wt]);
#pragma unroll
    for (int k = 0; k < 16; ++k) {
        const int d = 4 * k + tq;
        imA[0][d][h_ld] = __float2bfloat16(iraw[k].x);
        imA[1][d][h_ld] = __float2bfloat16(iraw[k].y);
    }
    __syncthreads();   // operands ready

    // ---- Phase 4: MFMA GEMM: C[d,z] = sum_h A[d,h] * B[h,z], per wt.
    // 4 waves x (2 M-tiles x 2 N-tiles) x K=64 (2 k-steps). ----
    const int lane  = t & 63;
    const int wv    = t >> 6;
    const int dbase = (wv >> 1) << 5;    // 0 / 32
    const int zbase = (wv & 1) << 5;     // 0 / 32
    const int fr    = lane & 15;
    const int kg    = (lane >> 4) << 3;  // k-group: 0,8,16,24

    f32x4 acc[WT][2][2] = {};
#pragma unroll
    for (int wt = 0; wt < WT; ++wt)
#pragma unroll
        for (int ks = 0; ks < 2; ++ks) {
            const int k = (ks << 5) + kg;
            const bf16x8 a0 = *(const bf16x8*)&imA[wt][dbase + fr][k];
            const bf16x8 a1 = *(const bf16x8*)&imA[wt][dbase + 16 + fr][k];
            const bf16x8 b0 = *(const bf16x8*)&pbT[wt][zbase + fr][k];
            const bf16x8 b1 = *(const bf16x8*)&pbT[wt][zbase + 16 + fr][k];
            acc[wt][0][0] = __builtin_amdgcn_mfma_f32_16x16x32_bf16(a0, b0, acc[wt][0][0], 0, 0, 0);
            acc[wt][0][1] = __builtin_amdgcn_mfma_f32_16x16x32_bf16(a0, b1, acc[wt][0][1], 0, 0, 0);
            acc[wt][1][0] = __builtin_amdgcn_mfma_f32_16x16x32_bf16(a1, b0, acc[wt][1][0], 0, 0, 0);
            acc[wt][1][1] = __builtin_amdgcn_mfma_f32_16x16x32_bf16(a1, b1, acc[wt][1][1], 0, 0, 0);
        }

    // ---- Phase 5: write image_polar. C/D layout: col=lane&15, row=(lane>>4)*4+r ----
    const int r0 = (lane >> 4) << 2;
#pragma unroll
    for (int i = 0; i < 2; ++i)
#pragma unroll
        for (int j = 0; j < 2; ++j)
#pragma unroll
            for (int r = 0; r < 4; ++r) {
                const int d = dbase + (i << 4) + r0 + r;
                const int z = zbase + (j << 4) + fr;
                float2 o;
                o.x = acc[0][i][j][r];
                o.y = acc[1][i][j][r];
                *(float2*)(out_img + (((size_t)(b * D_ + d)) * Z_ + z) * W_ + w0) = o;
            }
}

extern "C" void kernel_launch(void* const* d_in, const int* in_sizes, int n_in,
                              void* d_out, int out_size, void* d_ws, size_t ws_size,
                              hipStream_t stream) {
    const float* image = (const float*)d_in[0];
    const float* polar = (const float*)d_in[1];
    float* out_img  = (float*)d_out;
    float* out_cell = out_img + (size_t)B_ * D_ * Z_ * W_;
    dim3 grid(B_ * (W_ / WT));   // 2048 blocks
    polar_proj_kernel<<<grid, 256, 0, stream>>>(image, polar, out_img, out_cell);
}

// Round 4
// 56.008 us; speedup vs baseline: 1.5812x; 1.3990x over previous
//
#include <hip/hip_runtime.h>
#include <hip/hip_bf16.h>
#include <math.h>

// image: (B=32, D=64, H=64, W=128) f32
// polar_log_depths: (B=32, H=64, W=128, S=64) f32
// outputs: image_polar (B,D,Z=64,W) f32, cell_score (B,W,Z) f32, concat flat.
#define B_ 32
#define D_ 64
#define H_ 64
#define W_ 128
#define S_ 64
#define Z_ 64
#define WT 4

typedef __attribute__((ext_vector_type(8))) short bf16x8;
typedef __attribute__((ext_vector_type(4))) float f32x4;

static __device__ __forceinline__ short f2bf(float f) {
    union { __hip_bfloat16 h; short s; } u;
    u.h = __float2bfloat16(f);
    return u.s;
}

// LDS layout: per w-plane 8192 B of [64 rows][128 B], 16B-slot XOR-swizzled:
//   element (row, e) lives at row*128 + (((e>>3) ^ (row&7))<<4) + (e&7)*2
// This puts every b128 fragment read/write at the 8-accesses-per-bank floor.
__global__ __launch_bounds__(256, 2)
void polar_proj_kernel(const float* __restrict__ image,
                       const float* __restrict__ polar,
                       float* __restrict__ out_img,
                       float* __restrict__ out_cell) {
    __shared__ __align__(16) unsigned char sP[WT * 64 * 128];  // polar bf16 [w][h][s] -> prob^T bf16 [w][z][h] (aliased)
    __shared__ __align__(16) unsigned char sA[WT * 64 * 128];  // image bf16 [w][d][h]

    const int t = threadIdx.x;

    // XCD-bijective swizzle (grid 1024, %8==0): adjacent w-tiles share image/
    // output cache lines -> same XCD L2.
    const int cpx = gridDim.x >> 3;
    const int logical = (blockIdx.x & 7) * cpx + (blockIdx.x >> 3);
    const int b  = logical >> 5;           // / (W/WT)
    const int w0 = (logical & 31) << 2;    // w-tile base

    // ---- 1. issue image gather loads first (latency hides under phases 2-5) ----
    const int h_im = t & 63;               // lane -> h
    const int dq   = t >> 6;
    float4 ireg[16];
#pragma unroll
    for (int j = 0; j < 16; ++j) {
        const int d = dq + 4 * j;
        ireg[j] = *(const float4*)(image + ((size_t)((b * D_ + d) * H_ + h_im)) * W_ + w0);
    }

    // ---- 2. polar loads (coalesced: 4 lanes x 16B per row; 64 rows/pass) ----
    const int q  = t & 3;
    const int r2 = t >> 2;
    float4 preg[16];
#pragma unroll
    for (int p = 0; p < 4; ++p) {
        const int rr = p * 64 + r2;        // rr = w*64 + h, 0..255
        const int w  = rr >> 6, h = rr & 63;
        const float* src = polar + ((size_t)((b * H_ + h) * W_ + w0 + w)) * S_ + q * 16;
#pragma unroll
        for (int k = 0; k < 4; ++k)
            preg[p * 4 + k] = *(const float4*)(src + k * 4);
    }
    // ---- 3. cvt + swizzled PL writes (b128) ----
#pragma unroll
    for (int p = 0; p < 4; ++p) {
        const int rr = p * 64 + r2;
        const int w  = rr >> 6, h = rr & 63;
#pragma unroll
        for (int c = 0; c < 2; ++c) {
            bf16x8 v;
#pragma unroll
            for (int e = 0; e < 8; ++e)
                v[e] = f2bf(((const float*)&preg[p * 4 + c * 2 + (e >> 2)])[e & 3]);
            *(bf16x8*)(sP + w * 8192 + h * 128 + ((((q << 1) | c) ^ (h & 7)) << 4)) = v;
        }
    }
    __syncthreads();   // PL ready

    // ---- 4. fused interp + softmax: thread owns one (z, w) fully ----
    const int wi = t & 3;
    const int z  = t >> 2;
    const float posf = (log2f(0.5f + 0.5f * (float)z) + 1.0f) * 10.5f;  // (63/6)
    int i0 = (int)floorf(posf);
    i0 = i0 < 0 ? 0 : (i0 > S_ - 1 ? S_ - 1 : i0);
    const int i1 = (i0 + 1 > S_ - 1) ? (S_ - 1) : (i0 + 1);
    const float wq = posf - (float)i0;

    // 8 precomputed swizzle pointers per operand -> reads use immediate offsets
    const unsigned char* base0 = sP + wi * 8192 + ((i0 & 7) << 1);
    const unsigned char* base1 = sP + wi * 8192 + ((i1 & 7) << 1);
    const int sx0 = (i0 >> 3) << 4;
    const int sx1 = (i1 >> 3) << 4;
    const unsigned char* p0[8];
    const unsigned char* p1[8];
#pragma unroll
    for (int hc = 0; hc < 8; ++hc) {
        p0[hc] = base0 + (sx0 ^ (hc << 4));
        p1[hc] = base1 + (sx1 ^ (hc << 4));
    }

    float sc[64];
    float mx[4] = {-1e30f, -1e30f, -1e30f, -1e30f};
#pragma unroll
    for (int h = 0; h < 64; ++h) {
        const float v0 = __bfloat162float(*(const __hip_bfloat16*)(p0[h & 7] + h * 128));
        const float v1 = __bfloat162float(*(const __hip_bfloat16*)(p1[h & 7] + h * 128));
        const float v = v0 + wq * (v1 - v0);
        sc[h] = v;
        mx[h & 3] = fmaxf(mx[h & 3], v);
    }
    const float m = fmaxf(fmaxf(mx[0], mx[1]), fmaxf(mx[2], mx[3]));
    float sm[4] = {0.f, 0.f, 0.f, 0.f};
#pragma unroll
    for (int h = 0; h < 64; ++h) {
        const float e = __expf(sc[h] - m);
        sc[h] = e;
        sm[h & 3] += e;
    }
    const float s = (sm[0] + sm[1]) + (sm[2] + sm[3]);
    out_cell[((size_t)b * W_ + w0 + wi) * Z_ + z] = m + logf(s);
    const float inv = 1.0f / s;
    __syncthreads();   // all PL reads done; safe to overwrite with prob^T

    // ---- 5. write prob^T bf16 (b128, swizzled) + image bf16 scatter ----
#pragma unroll
    for (int j = 0; j < 8; ++j) {
        bf16x8 v;
#pragma unroll
        for (int e = 0; e < 8; ++e)
            v[e] = f2bf(sc[j * 8 + e] * inv);
        *(bf16x8*)(sP + wi * 8192 + z * 128 + ((j ^ (z & 7)) << 4)) = v;
    }
#pragma unroll
    for (int j = 0; j < 16; ++j) {
        const int d = dq + 4 * j;
        unsigned char* dst = sA + d * 128 + (((h_im >> 3) ^ (d & 7)) << 4) + ((h_im & 7) << 1);
#pragma unroll
        for (int w = 0; w < 4; ++w)
            *(short*)(dst + w * 8192) = f2bf(((const float*)&ireg[j])[w]);
    }
    __syncthreads();   // operands ready

    // ---- 6. MFMA PV: wave wv owns d-tile mt=wv, all 4 w, all z ----
    const int lane = t & 63;
    const int wv   = t >> 6;
    const int fr   = lane & 15;
    const int lg   = lane >> 4;
    const int rowA = wv * 16 + fr;
    const int fx   = (fr & 7) << 4;

    f32x4 acc[4][4] = {};   // [w][nt]
#pragma unroll
    for (int w = 0; w < 4; ++w) {
        const unsigned char* aw = sA + w * 8192 + rowA * 128;
        const bf16x8 a0 = *(const bf16x8*)(aw + ((lg << 4) ^ fx));
        const bf16x8 a1 = *(const bf16x8*)(aw + (((4 + lg) << 4) ^ fx));
#pragma unroll
        for (int nt = 0; nt < 4; ++nt) {
            const unsigned char* bw = sP + w * 8192 + (nt * 16 + fr) * 128;
            const bf16x8 b0 = *(const bf16x8*)(bw + ((lg << 4) ^ fx));
            const bf16x8 b1 = *(const bf16x8*)(bw + (((4 + lg) << 4) ^ fx));
            acc[w][nt] = __builtin_amdgcn_mfma_f32_16x16x32_bf16(a0, b0, acc[w][nt], 0, 0, 0);
            acc[w][nt] = __builtin_amdgcn_mfma_f32_16x16x32_bf16(a1, b1, acc[w][nt], 0, 0, 0);
        }
    }

    // ---- 7. stores: float4 over w per (d,z) ----
#pragma unroll
    for (int nt = 0; nt < 4; ++nt)
#pragma unroll
        for (int r = 0; r < 4; ++r) {
            float4 o;
            o.x = acc[0][nt][r];
            o.y = acc[1][nt][r];
            o.z = acc[2][nt][r];
            o.w = acc[3][nt][r];
            const int d = wv * 16 + lg * 4 + r;
            const int zc = nt * 16 + fr;
            *(float4*)(out_img + ((size_t)((b * D_ + d) * Z_) + zc) * W_ + w0) = o;
        }
}

extern "C" void kernel_launch(void* const* d_in, const int* in_sizes, int n_in,
                              void* d_out, int out_size, void* d_ws, size_t ws_size,
                              hipStream_t stream) {
    const float* image = (const float*)d_in[0];
    const float* polar = (const float*)d_in[1];
    float* out_img  = (float*)d_out;
    float* out_cell = out_img + (size_t)B_ * D_ * Z_ * W_;
    dim3 grid(B_ * (W_ / WT));   // 1024 blocks
    polar_proj_kernel<<<grid, 256, 0, stream>>>(image, polar, out_img, out_cell);
}

// Round 5
// 53.913 us; speedup vs baseline: 1.6426x; 1.0389x over previous
//
#include <hip/hip_runtime.h>
#include <hip/hip_bf16.h>
#include <math.h>

// image: (B=32, D=64, H=64, W=128) f32
// polar_log_depths: (B=32, H=64, W=128, S=64) f32
// outputs: image_polar (B,D,Z=64,W) f32, cell_score (B,W,Z) f32, concat flat.
#define B_ 32
#define D_ 64
#define H_ 64
#define W_ 128
#define S_ 64
#define Z_ 64
#define WT 8

typedef __attribute__((ext_vector_type(8))) short bf16x8;
typedef __attribute__((ext_vector_type(4))) float f32x4;

static __device__ __forceinline__ short f2bf(float f) {
    union { __hip_bfloat16 h; short s; } u;
    u.h = __float2bfloat16(f);
    return u.s;
}

// Swizzled byte offset of a 16B column-octet slot: plane w (0..7), row (0..63),
// column octet (0..7). slot = (oct ^ row ^ w) & 7 — bijective per row, spreads
// banks across rows AND planes (planes are 8192 B apart = bank-aliased).
static __device__ __forceinline__ int swz(int w, int row, int oct) {
    return w * 8192 + row * 128 + (((oct ^ row ^ w) & 7) << 4);
}

__global__ __launch_bounds__(1024, 4)
void polar_proj_kernel(const float* __restrict__ image,
                       const float* __restrict__ polar,
                       float* __restrict__ out_img,
                       float* __restrict__ out_cell) {
    __shared__ __align__(16) unsigned char sP[WT * 8192];  // polar bf16 [w][h][s] -> prob^T [w][z][h]
    __shared__ __align__(16) unsigned char sA[WT * 8192];  // image bf16 [w][d][h]

    const int t = threadIdx.x;

    // XCD-bijective swizzle: grid 512 (%8==0); adjacent w-tiles (shared image/
    // output lines) land on the same XCD L2.
    const int cpx = gridDim.x >> 3;                       // 64
    const int logical = (blockIdx.x & 7) * cpx + (blockIdx.x >> 3);
    const int b  = logical >> 4;
    const int w0 = (logical & 15) << 3;

    // ---- 1. image loads: lane pairs split each (d,h) 32B w-segment ->
    //         32 line-touches per instr (vs 64 with lane->h mapping). ----
    const int wq = t & 1;                                 // w-half (float4)
    float4 ir[8];
#pragma unroll
    for (int i = 0; i < 8; ++i) {
        const int p = i * 512 + (t >> 1);                 // (d,h) pair, 0..4095
        const int d = p >> 6, h = p & 63;
        ir[i] = *(const float4*)(image + ((size_t)((b * D_ + d) * H_ + h)) * W_ + w0 + wq * 4);
    }

    // ---- 2. polar loads: 4 lanes x 16B per 256B row -> 2 lanes/line. ----
    const int q4 = t & 3;
    const int rbase = t >> 2;                             // 0..255
    float4 pr[8];
#pragma unroll
    for (int rp = 0; rp < 2; ++rp) {
        const int rr = rbase + rp * 256;                  // rr = w*64 + h
        const int w = rr >> 6, h = rr & 63;
        const float* src = polar + ((size_t)((b * H_ + h) * W_ + w0 + w)) * S_ + q4 * 16;
#pragma unroll
        for (int k = 0; k < 4; ++k)
            pr[rp * 4 + k] = *(const float4*)(src + k * 4);
    }

    // ---- 3. image -> sA (bf16, swizzled). Scalar b16 writes, banks spread
    //         by h-octet within slot + slot XOR -> ~2-way (free). ----
#pragma unroll
    for (int i = 0; i < 8; ++i) {
        const int p = i * 512 + (t >> 1);
        const int d = p >> 6, h = p & 63;
#pragma unroll
        for (int c = 0; c < 4; ++c) {
            const int w = wq * 4 + c;
            *(short*)(sA + swz(w, d, h >> 3) + ((h & 7) << 1)) = f2bf(((const float*)&ir[i])[c]);
        }
    }

    // ---- 4. polar -> sP (bf16x8 b128, swizzled, at bank floor). ----
#pragma unroll
    for (int rp = 0; rp < 2; ++rp) {
        const int rr = rbase + rp * 256;
        const int w = rr >> 6, h = rr & 63;
#pragma unroll
        for (int c = 0; c < 2; ++c) {
            bf16x8 v;
#pragma unroll
            for (int e = 0; e < 8; ++e)
                v[e] = f2bf(((const float*)&pr[rp * 4 + c * 2 + (e >> 2)])[e & 3]);
            *(bf16x8*)(sP + swz(w, h, q4 * 2 + c)) = v;
        }
    }
    __syncthreads();   // polar staged

    // ---- 5. fused interp + softmax: thread = (w, z, h-half); pair via shfl. ----
    const int wsm  = t >> 7;                              // 0..7
    const int zsm  = (t >> 1) & 63;
    const int half = t & 1;
    const float posf = (log2f(0.5f + 0.5f * (float)zsm) + 1.0f) * 10.5f;  // (63/6)
    int i0 = (int)floorf(posf);
    i0 = i0 < 0 ? 0 : (i0 > S_ - 1 ? S_ - 1 : i0);
    const int i1 = (i0 + 1 > S_ - 1) ? (S_ - 1) : (i0 + 1);
    const float wqf = posf - (float)i0;

    const unsigned char* pl = sP + wsm * 8192;
    const int lo0 = (i0 & 7) << 1, lo1 = (i1 & 7) << 1;
    const unsigned char* p0[8];
    const unsigned char* p1[8];
#pragma unroll
    for (int hc = 0; hc < 8; ++hc) {
        p0[hc] = pl + ((((i0 >> 3) ^ hc ^ wsm) & 7) << 4) + lo0;
        p1[hc] = pl + ((((i1 >> 3) ^ hc ^ wsm) & 7) << 4) + lo1;
    }

    float e[32];
    float mx0 = -1e30f, mx1 = -1e30f;
#pragma unroll
    for (int j = 0; j < 32; ++j) {
        const int h = half * 32 + j;
        const float v0 = __bfloat162float(*(const __hip_bfloat16*)(p0[j & 7] + h * 128));
        const float v1 = __bfloat162float(*(const __hip_bfloat16*)(p1[j & 7] + h * 128));
        const float v = v0 + wqf * (v1 - v0);
        e[j] = v;
        if (j & 1) mx1 = fmaxf(mx1, v); else mx0 = fmaxf(mx0, v);
    }
    float m = fmaxf(mx0, mx1);
    m = fmaxf(m, __shfl_xor(m, 1));
    float s0 = 0.f, s1 = 0.f;
#pragma unroll
    for (int j = 0; j < 32; ++j) {
        const float ev = __expf(e[j] - m);
        e[j] = ev;
        if (j & 1) s1 += ev; else s0 += ev;
    }
    float s = s0 + s1;
    s += __shfl_xor(s, 1);
    if (half == 0)
        out_cell[((size_t)b * W_ + w0 + wsm) * Z_ + zsm] = m + logf(s);
    const float inv = 1.0f / s;
    __syncthreads();   // all raw-polar reads done; safe to overwrite

    // ---- 6. prob^T -> sP rows z (bf16x8 b128, swizzled, bank floor). ----
#pragma unroll
    for (int c = 0; c < 4; ++c) {
        bf16x8 v;
#pragma unroll
        for (int ee = 0; ee < 8; ++ee)
            v[ee] = f2bf(e[c * 8 + ee] * inv);
        *(bf16x8*)(sP + swz(wsm, zsm, half * 4 + c)) = v;
    }
    __syncthreads();   // operands ready

    // ---- 7. MFMA GEMM: wave (mt,nt) does 16d x 16z x 8w, K=64. ----
    const int lane = t & 63;
    const int wv   = t >> 6;
    const int mt   = wv >> 2, nt = wv & 3;
    const int fr   = lane & 15, lg = lane >> 4;
    const int rowA = mt * 16 + fr;
    const int rowB = nt * 16 + fr;

    f32x4 acc[8] = {};
#pragma unroll
    for (int w = 0; w < 8; ++w)
#pragma unroll
        for (int ks = 0; ks < 2; ++ks) {
            const bf16x8 a  = *(const bf16x8*)(sA + swz(w, rowA, ks * 4 + lg));
            const bf16x8 bb = *(const bf16x8*)(sP + swz(w, rowB, ks * 4 + lg));
            acc[w] = __builtin_amdgcn_mfma_f32_16x16x32_bf16(a, bb, acc[w], 0, 0, 0);
        }
    __syncthreads();   // all GEMM LDS reads done; reuse LDS for store regroup

    // ---- 8. wave-local store regroup: remap (lane,reg)->(d,z,w) so store
    //         instr lane-pairs share out lines (32 transactions vs 64). ----
    unsigned char* rg = (wv & 8) ? (sA + (wv & 7) * 8192) : (sP + (wv & 7) * 8192);
    // write: value acc[w][r] is (di = lg*4+r, zi = fr, w); li = zi*4 + lg + r*64
#pragma unroll
    for (int r = 0; r < 4; ++r) {
        const int li = fr * 4 + lg + r * 64;
#pragma unroll
        for (int wp = 0; wp < 4; ++wp) {
            float2 v;
            v.x = acc[wp * 2][r];
            v.y = acc[wp * 2 + 1][r];
            *(float2*)(rg + li * 32 + wp * 8) = v;
        }
    }
    __syncthreads();
    const unsigned char* rgc = rg;
#pragma unroll
    for (int i = 0; i < 8; ++i) {
        const int dz = (lane >> 1) + i * 32;              // di*16 + zi
        const int wh = lane & 1;
        const int di = dz >> 4, zi = dz & 15;
        const int li = zi * 4 + (di >> 2) + (di & 3) * 64;
        const float4 v = *(const float4*)(rgc + li * 32 + wh * 16);
        const int d = mt * 16 + di;
        const int z = nt * 16 + zi;
        *(float4*)(out_img + ((size_t)((b * D_ + d) * Z_) + z) * W_ + w0 + wh * 4) = v;
    }
}

extern "C" void kernel_launch(void* const* d_in, const int* in_sizes, int n_in,
                              void* d_out, int out_size, void* d_ws, size_t ws_size,
                              hipStream_t stream) {
    const float* image = (const float*)d_in[0];
    const float* polar = (const float*)d_in[1];
    float* out_img  = (float*)d_out;
    float* out_cell = out_img + (size_t)B_ * D_ * Z_ * W_;
    dim3 grid(B_ * (W_ / WT));   // 512 blocks
    polar_proj_kernel<<<grid, 1024, 0, stream>>>(image, polar, out_img, out_cell);
}

// Round 6
// 52.017 us; speedup vs baseline: 1.7025x; 1.0364x over previous
//
#include <hip/hip_runtime.h>
#include <hip/hip_bf16.h>
#include <math.h>

// image: (B=32, D=64, H=64, W=128) f32
// polar_log_depths: (B=32, H=64, W=128, S=64) f32
// outputs: image_polar (B,D,Z=64,W) f32, cell_score (B,W,Z) f32, concat flat.
#define B_ 32
#define D_ 64
#define H_ 64
#define W_ 128
#define S_ 64
#define Z_ 64
#define WT 8

typedef __attribute__((ext_vector_type(8))) short bf16x8;
typedef __attribute__((ext_vector_type(4))) float f32x4;

static __device__ __forceinline__ short f2bf(float f) {
    union { __hip_bfloat16 h; short s; } u;
    u.h = __float2bfloat16(f);
    return u.s;
}

// Swizzled byte offset of a 16B column-octet slot in an 8KB [64][128B] plane.
static __device__ __forceinline__ int swz(int w, int row, int oct) {
    return w * 8192 + row * 128 + (((oct ^ row ^ w) & 7) << 4);
}
static __device__ __forceinline__ int swz0(int row, int oct) {
    return row * 128 + (((oct ^ row) & 7) << 4);
}

__global__ __launch_bounds__(1024, 4)
void polar_proj_kernel(const float* __restrict__ image,
                       const float* __restrict__ polar,
                       float* __restrict__ out_img,
                       float* __restrict__ out_cell) {
    __shared__ __align__(16) unsigned char sP[WT * 8192];  // polar bf16 [w][h][s] -> prob^T [w][z][h]
    __shared__ __align__(16) unsigned char sA[WT * 8192];  // image bf16 [w][d][h]
    __shared__ __align__(16) unsigned char sWz[8192];      // Wz^T bf16 [z][s]

    const int t = threadIdx.x;

    // XCD-bijective swizzle: grid 512 (%8==0).
    const int cpx = gridDim.x >> 3;
    const int logical = (blockIdx.x & 7) * cpx + (blockIdx.x >> 3);
    const int b  = logical >> 4;
    const int w0 = (logical & 15) << 3;

    // ---- 1. image loads: lane pairs split each (d,h) 32B w-segment. ----
    const int wq = t & 1;
    float4 ir[8];
#pragma unroll
    for (int i = 0; i < 8; ++i) {
        const int p = i * 512 + (t >> 1);
        const int d = p >> 6, h = p & 63;
        ir[i] = *(const float4*)(image + ((size_t)((b * D_ + d) * H_ + h)) * W_ + w0 + wq * 4);
    }

    // ---- 2. polar loads: 4 lanes x 16B per 256B row. ----
    const int q4 = t & 3;
    const int rbase = t >> 2;
    float4 pr[8];
#pragma unroll
    for (int rp = 0; rp < 2; ++rp) {
        const int rr = rbase + rp * 256;      // rr = w*64 + h
        const int w = rr >> 6, h = rr & 63;
        const float* src = polar + ((size_t)((b * H_ + h) * W_ + w0 + w)) * S_ + q4 * 16;
#pragma unroll
        for (int k = 0; k < 4; ++k)
            pr[rp * 4 + k] = *(const float4*)(src + k * 4);
    }

    // ---- 0. build Wz^T (constant interp matrix) — overlaps load latency. ----
    {
        const int z  = t >> 4;
        const int s4 = (t & 15) << 2;
        const float posf = (log2f(0.5f + 0.5f * (float)z) + 1.0f) * 10.5f;  // (63/6)
        int i0 = (int)floorf(posf);
        i0 = i0 < 0 ? 0 : (i0 > S_ - 1 ? S_ - 1 : i0);
        const int i1 = (i0 + 1 > S_ - 1) ? (S_ - 1) : (i0 + 1);
        const float wz = posf - (float)i0;
        short e4[4];
#pragma unroll
        for (int c = 0; c < 4; ++c) {
            const int s = s4 + c;
            float v = 0.0f;
            if (s == i0) v += 1.0f - wz;
            if (s == i1) v += wz;
            e4[c] = f2bf(v);
        }
        int2 pk;
        pk.x = (e4[0] & 0xffff) | (e4[1] << 16);
        pk.y = (e4[2] & 0xffff) | (e4[3] << 16);
        *(int2*)(sWz + swz0(z, s4 >> 3) + ((s4 & 7) << 1)) = pk;
    }

    // ---- 3. image -> sA (bf16, swizzled). ----
#pragma unroll
    for (int i = 0; i < 8; ++i) {
        const int p = i * 512 + (t >> 1);
        const int d = p >> 6, h = p & 63;
#pragma unroll
        for (int c = 0; c < 4; ++c) {
            const int w = wq * 4 + c;
            *(short*)(sA + swz(w, d, h >> 3) + ((h & 7) << 1)) = f2bf(((const float*)&ir[i])[c]);
        }
    }

    // ---- 4. polar -> sP (bf16x8 b128, swizzled). ----
#pragma unroll
    for (int rp = 0; rp < 2; ++rp) {
        const int rr = rbase + rp * 256;
        const int w = rr >> 6, h = rr & 63;
#pragma unroll
        for (int c = 0; c < 2; ++c) {
            bf16x8 v;
#pragma unroll
            for (int e = 0; e < 8; ++e)
                v[e] = f2bf(((const float*)&pr[rp * 4 + c * 2 + (e >> 2)])[e & 3]);
            *(bf16x8*)(sP + swz(w, h, q4 * 2 + c)) = v;
        }
    }
    __syncthreads();   // staging + Wz^T ready

    // ---- 5. interp as MFMA: D[h,z] = sum_s polar[h,s]*Wz[s,z].
    //      wave = (w-plane, z-half); mt=4 (h), nt=2 (z), ks=2 (s). ----
    const int lane = t & 63;
    const int wv   = t >> 6;
    const int fr   = lane & 15, lg = lane >> 4;
    const int wS   = wv >> 1, zh = wv & 1;

    f32x4 sacc[4][2] = {};
#pragma unroll
    for (int ks = 0; ks < 2; ++ks) {
        const bf16x8 bf0 = *(const bf16x8*)(sWz + swz0(zh * 32 + fr,      ks * 4 + lg));
        const bf16x8 bf1 = *(const bf16x8*)(sWz + swz0(zh * 32 + 16 + fr, ks * 4 + lg));
#pragma unroll
        for (int mt = 0; mt < 4; ++mt) {
            const bf16x8 a = *(const bf16x8*)(sP + swz(wS, mt * 16 + fr, ks * 4 + lg));
            sacc[mt][0] = __builtin_amdgcn_mfma_f32_16x16x32_bf16(a, bf0, sacc[mt][0], 0, 0, 0);
            sacc[mt][1] = __builtin_amdgcn_mfma_f32_16x16x32_bf16(a, bf1, sacc[mt][1], 0, 0, 0);
        }
    }

    // ---- softmax over h, in-register, no max-subtract (|score| <~ 6). ----
    float ex[4][2][4];
    float ss0 = 0.0f, ss1 = 0.0f;
#pragma unroll
    for (int mt = 0; mt < 4; ++mt)
#pragma unroll
        for (int r = 0; r < 4; ++r) {
            const float e0 = __expf(sacc[mt][0][r]);
            const float e1 = __expf(sacc[mt][1][r]);
            ex[mt][0][r] = e0;
            ex[mt][1][r] = e1;
            ss0 += e0;
            ss1 += e1;
        }
    ss0 += __shfl_xor(ss0, 16);
    ss0 += __shfl_xor(ss0, 32);
    ss1 += __shfl_xor(ss1, 16);
    ss1 += __shfl_xor(ss1, 32);
    if (lg == 0) {
        float* oc = out_cell + ((size_t)b * W_ + w0 + wS) * Z_ + zh * 32 + fr;
        oc[0]  = __logf(ss0);
        oc[16] = __logf(ss1);
    }
    const float inv0 = 1.0f / ss0;
    const float inv1 = 1.0f / ss1;
    __syncthreads();   // all S-GEMM reads of sP done; safe to overwrite

    // ---- 6. prob^T -> sP rows z (b64 packs of 4 h-contiguous bf16). ----
#pragma unroll
    for (int nt = 0; nt < 2; ++nt) {
        const int zrow = zh * 32 + nt * 16 + fr;
        const float inv = nt ? inv1 : inv0;
#pragma unroll
        for (int mt = 0; mt < 4; ++mt) {
            const short p0 = f2bf(ex[mt][nt][0] * inv);
            const short p1 = f2bf(ex[mt][nt][1] * inv);
            const short p2 = f2bf(ex[mt][nt][2] * inv);
            const short p3 = f2bf(ex[mt][nt][3] * inv);
            int2 pk;
            pk.x = (p0 & 0xffff) | (p1 << 16);
            pk.y = (p2 & 0xffff) | (p3 << 16);
            *(int2*)(sP + swz(wS, zrow, mt * 2 + (lg >> 1)) + ((lg & 1) << 3)) = pk;
        }
    }
    __syncthreads();   // operands ready

    // ---- 7. PV GEMM: wave (mt,nt) does 16d x 16z x 8w, K=64. ----
    const int mtp = wv >> 2, ntp = wv & 3;
    const int rowA = mtp * 16 + fr;
    const int rowB = ntp * 16 + fr;
    f32x4 acc[8] = {};
#pragma unroll
    for (int w = 0; w < 8; ++w)
#pragma unroll
        for (int ks = 0; ks < 2; ++ks) {
            const bf16x8 a  = *(const bf16x8*)(sA + swz(w, rowA, ks * 4 + lg));
            const bf16x8 bb = *(const bf16x8*)(sP + swz(w, rowB, ks * 4 + lg));
            acc[w] = __builtin_amdgcn_mfma_f32_16x16x32_bf16(a, bb, acc[w], 0, 0, 0);
        }
    __syncthreads();   // all GEMM LDS reads done; reuse LDS for store regroup

    // ---- 8. wave-local store regroup: lane pairs share output lines. ----
    unsigned char* rg = (wv & 8) ? (sA + (wv & 7) * 8192) : (sP + (wv & 7) * 8192);
#pragma unroll
    for (int r = 0; r < 4; ++r) {
        const int li = fr * 4 + lg + r * 64;
#pragma unroll
        for (int wp = 0; wp < 4; ++wp) {
            float2 v;
            v.x = acc[wp * 2][r];
            v.y = acc[wp * 2 + 1][r];
            *(float2*)(rg + li * 32 + wp * 8) = v;
        }
    }
    __syncthreads();
    const unsigned char* rgc = rg;
#pragma unroll
    for (int i = 0; i < 8; ++i) {
        const int dz = (lane >> 1) + i * 32;
        const int wh = lane & 1;
        const int di = dz >> 4, zi = dz & 15;
        const int li = zi * 4 + (di >> 2) + (di & 3) * 64;
        const float4 v = *(const float4*)(rgc + li * 32 + wh * 16);
        const int d = mtp * 16 + di;
        const int z = ntp * 16 + zi;
        *(float4*)(out_img + ((size_t)((b * D_ + d) * Z_) + z) * W_ + w0 + wh * 4) = v;
    }
}

extern "C" void kernel_launch(void* const* d_in, const int* in_sizes, int n_in,
                              void* d_out, int out_size, void* d_ws, size_t ws_size,
                              hipStream_t stream) {
    const float* image = (const float*)d_in[0];
    const float* polar = (const float*)d_in[1];
    float* out_img  = (float*)d_out;
    float* out_cell = out_img + (size_t)B_ * D_ * Z_ * W_;
    dim3 grid(B_ * (W_ / WT));   // 512 blocks
    polar_proj_kernel<<<grid, 1024, 0, stream>>>(image, polar, out_img, out_cell);
}

// Round 7
// 51.928 us; speedup vs baseline: 1.7054x; 1.0017x over previous
//
#include <hip/hip_runtime.h>
#include <hip/hip_bf16.h>
#include <math.h>

// image: (B=32, D=64, H=64, W=128) f32
// polar_log_depths: (B=32, H=64, W=128, S=64) f32
// outputs: image_polar (B,D,Z=64,W) f32, cell_score (B,W,Z) f32, concat flat.
#define B_ 32
#define D_ 64
#define H_ 64
#define W_ 128
#define S_ 64
#define Z_ 64
#define WT 8

typedef __attribute__((ext_vector_type(8))) short bf16x8;
typedef __attribute__((ext_vector_type(4))) float f32x4;

static __device__ __forceinline__ short f2bf(float f) {
    union { __hip_bfloat16 h; short s; } u;
    u.h = __float2bfloat16(f);
    return u.s;
}

// Swizzled byte offset of a 16B column-octet slot in an 8KB [64][128B] plane.
static __device__ __forceinline__ int swz(int w, int row, int oct) {
    return w * 8192 + row * 128 + (((oct ^ row ^ w) & 7) << 4);
}
static __device__ __forceinline__ int swz0(int row, int oct) {
    return row * 128 + (((oct ^ row) & 7) << 4);
}

__global__ __launch_bounds__(1024, 4)
void polar_proj_kernel(const float* __restrict__ image,
                       const float* __restrict__ polar,
                       float* __restrict__ out_img,
                       float* __restrict__ out_cell) {
    __shared__ __align__(16) unsigned char sP[WT * 8192];  // polar bf16 [w][h][s] -> prob^T [w][z][h]
    __shared__ __align__(16) unsigned char sA[WT * 8192];  // image bf16 [w][d][h]
    __shared__ __align__(16) unsigned char sWz[8192];      // Wz^T bf16 [z][s]

    const int t = threadIdx.x;

    // XCD-bijective swizzle: grid 512 (%8==0).
    const int cpx = gridDim.x >> 3;
    const int logical = (blockIdx.x & 7) * cpx + (blockIdx.x >> 3);
    const int b  = logical >> 4;
    const int w0 = (logical & 15) << 3;

    // ---- 1. image loads: lane pairs split each (d,h) 32B w-segment. ----
    const int wq = t & 1;
    float4 ir[8];
#pragma unroll
    for (int i = 0; i < 8; ++i) {
        const int p = i * 512 + (t >> 1);
        const int d = p >> 6, h = p & 63;
        ir[i] = *(const float4*)(image + ((size_t)((b * D_ + d) * H_ + h)) * W_ + w0 + wq * 4);
    }

    // ---- 2. polar loads: 4 lanes x 16B per 256B row. ----
    const int q4 = t & 3;
    const int rbase = t >> 2;
    float4 pr[8];
#pragma unroll
    for (int rp = 0; rp < 2; ++rp) {
        const int rr = rbase + rp * 256;      // rr = w*64 + h
        const int w = rr >> 6, h = rr & 63;
        const float* src = polar + ((size_t)((b * H_ + h) * W_ + w0 + w)) * S_ + q4 * 16;
#pragma unroll
        for (int k = 0; k < 4; ++k)
            pr[rp * 4 + k] = *(const float4*)(src + k * 4);
    }

    // ---- 0. build Wz^T (constant interp matrix) — overlaps load latency. ----
    {
        const int z  = t >> 4;
        const int s4 = (t & 15) << 2;
        const float posf = (log2f(0.5f + 0.5f * (float)z) + 1.0f) * 10.5f;  // (63/6)
        int i0 = (int)floorf(posf);
        i0 = i0 < 0 ? 0 : (i0 > S_ - 1 ? S_ - 1 : i0);
        const int i1 = (i0 + 1 > S_ - 1) ? (S_ - 1) : (i0 + 1);
        const float wz = posf - (float)i0;
        short e4[4];
#pragma unroll
        for (int c = 0; c < 4; ++c) {
            const int s = s4 + c;
            float v = 0.0f;
            if (s == i0) v += 1.0f - wz;
            if (s == i1) v += wz;
            e4[c] = f2bf(v);
        }
        int2 pk;
        pk.x = (e4[0] & 0xffff) | (e4[1] << 16);
        pk.y = (e4[2] & 0xffff) | (e4[3] << 16);
        *(int2*)(sWz + swz0(z, s4 >> 3) + ((s4 & 7) << 1)) = pk;
    }

    // ---- 3. image -> sA (bf16, swizzled). ----
#pragma unroll
    for (int i = 0; i < 8; ++i) {
        const int p = i * 512 + (t >> 1);
        const int d = p >> 6, h = p & 63;
#pragma unroll
        for (int c = 0; c < 4; ++c) {
            const int w = wq * 4 + c;
            *(short*)(sA + swz(w, d, h >> 3) + ((h & 7) << 1)) = f2bf(((const float*)&ir[i])[c]);
        }
    }

    // ---- 4. polar -> sP (bf16x8 b128, swizzled). ----
#pragma unroll
    for (int rp = 0; rp < 2; ++rp) {
        const int rr = rbase + rp * 256;
        const int w = rr >> 6, h = rr & 63;
#pragma unroll
        for (int c = 0; c < 2; ++c) {
            bf16x8 v;
#pragma unroll
            for (int e = 0; e < 8; ++e)
                v[e] = f2bf(((const float*)&pr[rp * 4 + c * 2 + (e >> 2)])[e & 3]);
            *(bf16x8*)(sP + swz(w, h, q4 * 2 + c)) = v;
        }
    }
    __syncthreads();   // staging + Wz^T ready

    // ---- 5. interp as MFMA: D[h,z] = sum_s polar[h,s]*Wz[s,z].
    //      wave = (w-plane, z-half); mt=4 (h), nt=2 (z), ks=2 (s). ----
    const int lane = t & 63;
    const int wv   = t >> 6;
    const int fr   = lane & 15, lg = lane >> 4;
    const int wS   = wv >> 1, zh = wv & 1;

    f32x4 sacc[4][2] = {};
#pragma unroll
    for (int ks = 0; ks < 2; ++ks) {
        const bf16x8 bf0 = *(const bf16x8*)(sWz + swz0(zh * 32 + fr,      ks * 4 + lg));
        const bf16x8 bf1 = *(const bf16x8*)(sWz + swz0(zh * 32 + 16 + fr, ks * 4 + lg));
#pragma unroll
        for (int mt = 0; mt < 4; ++mt) {
            const bf16x8 a = *(const bf16x8*)(sP + swz(wS, mt * 16 + fr, ks * 4 + lg));
            sacc[mt][0] = __builtin_amdgcn_mfma_f32_16x16x32_bf16(a, bf0, sacc[mt][0], 0, 0, 0);
            sacc[mt][1] = __builtin_amdgcn_mfma_f32_16x16x32_bf16(a, bf1, sacc[mt][1], 0, 0, 0);
        }
    }

    // ---- softmax over h, in-register, no max-subtract (|score| <~ 6). ----
    float ex[4][2][4];
    float ss0 = 0.0f, ss1 = 0.0f;
#pragma unroll
    for (int mt = 0; mt < 4; ++mt)
#pragma unroll
        for (int r = 0; r < 4; ++r) {
            const float e0 = __expf(sacc[mt][0][r]);
            const float e1 = __expf(sacc[mt][1][r]);
            ex[mt][0][r] = e0;
            ex[mt][1][r] = e1;
            ss0 += e0;
            ss1 += e1;
        }
    ss0 += __shfl_xor(ss0, 16);
    ss0 += __shfl_xor(ss0, 32);
    ss1 += __shfl_xor(ss1, 16);
    ss1 += __shfl_xor(ss1, 32);
    if (lg == 0) {
        float* oc = out_cell + ((size_t)b * W_ + w0 + wS) * Z_ + zh * 32 + fr;
        oc[0]  = __logf(ss0);
        oc[16] = __logf(ss1);
    }
    const float inv0 = 1.0f / ss0;
    const float inv1 = 1.0f / ss1;
    __syncthreads();   // all S-GEMM reads of sP done; safe to overwrite

    // ---- 6. prob^T -> sP rows z (b64 packs of 4 h-contiguous bf16). ----
#pragma unroll
    for (int nt = 0; nt < 2; ++nt) {
        const int zrow = zh * 32 + nt * 16 + fr;
        const float inv = nt ? inv1 : inv0;
#pragma unroll
        for (int mt = 0; mt < 4; ++mt) {
            const short p0 = f2bf(ex[mt][nt][0] * inv);
            const short p1 = f2bf(ex[mt][nt][1] * inv);
            const short p2 = f2bf(ex[mt][nt][2] * inv);
            const short p3 = f2bf(ex[mt][nt][3] * inv);
            int2 pk;
            pk.x = (p0 & 0xffff) | (p1 << 16);
            pk.y = (p2 & 0xffff) | (p3 << 16);
            *(int2*)(sP + swz(wS, zrow, mt * 2 + (lg >> 1)) + ((lg & 1) << 3)) = pk;
        }
    }
    __syncthreads();   // operands ready

    // ---- 7. PV GEMM: wave (mt,nt) does 16d x 16z x 8w, K=64. ----
    const int mtp = wv >> 2, ntp = wv & 3;
    const int rowA = mtp * 16 + fr;
    const int rowB = ntp * 16 + fr;
    f32x4 acc[8] = {};
#pragma unroll
    for (int w = 0; w < 8; ++w)
#pragma unroll
        for (int ks = 0; ks < 2; ++ks) {
            const bf16x8 a  = *(const bf16x8*)(sA + swz(w, rowA, ks * 4 + lg));
            const bf16x8 bb = *(const bf16x8*)(sP + swz(w, rowB, ks * 4 + lg));
            acc[w] = __builtin_amdgcn_mfma_f32_16x16x32_bf16(a, bb, acc[w], 0, 0, 0);
        }
    __syncthreads();   // all GEMM LDS reads done; reuse LDS for store regroup

    // ---- 8. wave-local store regroup: lane pairs share output lines. ----
    unsigned char* rg = (wv & 8) ? (sA + (wv & 7) * 8192) : (sP + (wv & 7) * 8192);
#pragma unroll
    for (int r = 0; r < 4; ++r) {
        const int li = fr * 4 + lg + r * 64;
#pragma unroll
        for (int wp = 0; wp < 4; ++wp) {
            float2 v;
            v.x = acc[wp * 2][r];
            v.y = acc[wp * 2 + 1][r];
            *(float2*)(rg + li * 32 + wp * 8) = v;
        }
    }
    __syncthreads();
    const unsigned char* rgc = rg;
#pragma unroll
    for (int i = 0; i < 8; ++i) {
        const int dz = (lane >> 1) + i * 32;
        const int wh = lane & 1;
        const int di = dz >> 4, zi = dz & 15;
        const int li = zi * 4 + (di >> 2) + (di & 3) * 64;
        const float4 v = *(const float4*)(rgc + li * 32 + wh * 16);
        const int d = mtp * 16 + di;
        const int z = ntp * 16 + zi;
        *(float4*)(out_img + ((size_t)((b * D_ + d) * Z_) + z) * W_ + w0 + wh * 4) = v;
    }
}

extern "C" void kernel_launch(void* const* d_in, const int* in_sizes, int n_in,
                              void* d_out, int out_size, void* d_ws, size_t ws_size,
                              hipStream_t stream) {
    const float* image = (const float*)d_in[0];
    const float* polar = (const float*)d_in[1];
    float* out_img  = (float*)d_out;
    float* out_cell = out_img + (size_t)B_ * D_ * Z_ * W_;
    dim3 grid(B_ * (W_ / WT));   // 512 blocks
    polar_proj_kernel<<<grid, 1024, 0, stream>>>(image, polar, out_img, out_cell);
}